// Round 9
// baseline (210.597 us; speedup 1.0000x reference)
//
#include <hip/hip_runtime.h>
#include <hip/hip_fp16.h>
#include <math.h>

// Problem constants (fixed by setup_inputs): x is (8,1024,1024,2) fp32, k=61
#define NB 8
#define HH 1024
#define WW 1024
#define RAD 30
#define KS 61
#define ROWSZ 2048             /* floats per row (1024 px x 2 ch) */
#define IMGSZ (HH * ROWSZ)
#define STR2 1024              /* pixels per row (uint2/float2/unsigned stride) */
#define NCOL2 (NB * STR2)      /* 8192 pixel columns */
#define VSEGH 32               /* 32 rows/seg: 1024 blocks at 8B lanes */
#define VNSEG (HH / VSEGH)     /* 32 */
#define EPSV 1e-7f
#define SCALEV (1.0f / (float)(KS * KS * 2))
#define PDW (WW + WW / 8)
#define PD(i) ((i) + ((i) >> 3))

// ---- bf16 pack/unpack (manual, round-to-nearest-even) ----------------------
__device__ __forceinline__ unsigned bf16_rn(float f) {
    unsigned u = __float_as_uint(f);
    return (u + 0x7FFFu + ((u >> 16) & 1u)) >> 16;
}
__device__ __forceinline__ unsigned pk2(float a, float b) {
    return bf16_rn(a) | (bf16_rn(b) << 16);
}
__device__ __forceinline__ float2 up2(unsigned u) {
    return make_float2(__uint_as_float(u << 16),
                       __uint_as_float(u & 0xFFFF0000u));
}
// ---- fp16 pack/unpack (numerator plane) ------------------------------------
__device__ __forceinline__ unsigned pkh(float a, float b) {
    __half2 h = __floats2half2_rn(a, b);
    return *reinterpret_cast<unsigned*>(&h);
}
__device__ __forceinline__ float2 uph(unsigned u) {
    __half2 h = *reinterpret_cast<__half2*>(&u);
    return __half22float2(h);
}
__device__ __forceinline__ float2 f2add(float2 a, float2 b) {
    return make_float2(a.x + b.x, a.y + b.y);
}
__device__ __forceinline__ float2 f2sub(float2 a, float2 b) {
    return make_float2(a.x - b.x, a.y - b.y);
}
// fast single-instruction transcendentals (v_sqrt_f32 / v_rcp_f32, ~1 ulp)
__device__ __forceinline__ float sqrt_f(float x) { return __builtin_amdgcn_sqrtf(x); }
__device__ __forceinline__ float rcp_f(float x)  { return __builtin_amdgcn_rcpf(x); }

// ---------------------------------------------------------------------------
// K1: vertical 61-tap box-sum of x -> V1 (bf16-packed). 8B lanes (1 pixel),
// V32 -> 1024 blocks (4 blocks/CU, 16 waves/CU), double-buffered 8-row batches.
__global__ __launch_bounds__(256) void vbox_kernel(const float* __restrict__ in,
                                                   unsigned* __restrict__ out) {
    int tid = blockIdx.x * 256 + threadIdx.x;
    int col = tid & (NCOL2 - 1);
    int seg = tid >> 13;
    int n = col >> 10;
    int w2 = col & (STR2 - 1);
    const float2* ip = (const float2*)(in + (size_t)n * IMGSZ) + w2;
    unsigned* op = out + (size_t)n * (IMGSZ / 2) + w2;
    int h0 = seg * VSEGH;
    float2 S = make_float2(0.f, 0.f);
    int lo = h0 - RAD; if (lo < 0) lo = 0;
    int hiend = h0 + RAD; if (hiend > HH) hiend = HH;
    int h = lo;
    for (; h + 8 <= hiend; h += 8) {
        float2 W[8];
        #pragma unroll
        for (int i = 0; i < 8; ++i) W[i] = ip[(h + i) * STR2];
        __builtin_amdgcn_sched_barrier(0);
        #pragma unroll
        for (int i = 0; i < 8; ++i) S = f2add(S, W[i]);
    }
    for (; h < hiend; ++h) S = f2add(S, ip[h * STR2]);

    if (h0 >= RAD && h0 + VSEGH + RAD <= HH) {   // interior (bounds-based)
        const float2* lp = ip + (h0 + RAD) * STR2;
        const float2* tp = ip + (h0 - RAD) * STR2;
        unsigned* opp = op + (size_t)h0 * STR2;
        float2 LA[8], TA[8], LB[8], TB[8];
#define VB_LOAD(Lx, Tx, r) { \
        _Pragma("unroll") for (int i = 0; i < 8; ++i) Lx[i] = lp[((r) + i) * STR2]; \
        _Pragma("unroll") for (int i = 0; i < 8; ++i) Tx[i] = tp[((r) + i) * STR2]; \
        __builtin_amdgcn_sched_barrier(0); }
#define VB_CONS(Lx, Tx, r) { \
        _Pragma("unroll") for (int i = 0; i < 8; ++i) { \
            S = f2add(S, Lx[i]); \
            opp[((r) + i) * STR2] = pk2(S.x, S.y); \
            S = f2sub(S, Tx[i]); } }
        VB_LOAD(LA, TA, 0)
        VB_LOAD(LB, TB, 8)
        VB_CONS(LA, TA, 0)
        VB_LOAD(LA, TA, 16)
        VB_CONS(LB, TB, 8)
        VB_LOAD(LB, TB, 24)
        VB_CONS(LA, TA, 16)
        VB_CONS(LB, TB, 24)
#undef VB_LOAD
#undef VB_CONS
    } else {
        const float2 Z = make_float2(0.f, 0.f);
        for (int ho = h0; ho < h0 + VSEGH; ho += 4) {
            float2 a[4], b[4];
            #pragma unroll
            for (int i = 0; i < 4; ++i) {
                int ha = ho + i + RAD;
                a[i] = (ha < HH) ? ip[ha * STR2] : Z;
            }
            #pragma unroll
            for (int i = 0; i < 4; ++i) {
                int hb = ho + i - RAD;
                b[i] = (hb >= 0) ? ip[hb * STR2] : Z;
            }
            #pragma unroll
            for (int i = 0; i < 4; ++i) {
                S = f2add(S, a[i]);
                op[(size_t)(ho + i) * STR2] = pk2(S.x, S.y);
                S = f2sub(S, b[i]);
            }
        }
    }
}

__device__ inline float wave_incl_scan(float v) {
    int lane = threadIdx.x & 63;
    #pragma unroll
    for (int d = 1; d < 64; d <<= 1) {
        float o = __shfl_up(v, d, 64);
        if (lane >= d) v += o;
    }
    return v;
}

// ---------------------------------------------------------------------------
// K2': fused middle kernel, one block per row (unchanged from r8).
//   phase 1: prefix-scan V1 row -> horizontal box -> m; numerator out = x - m,
//            written fp16 into OH (aliases V1; same-block RAW->WAR, race-free).
//   phase 2: prefix-scan out, out^2 (LDS) -> 61-tap horizontal box sums,
//            written interleaved uint2{h1,h2} per pixel (bf16x2 each).
__global__ __launch_bounds__(256) void hmid_kernel(const unsigned* __restrict__ vsum,
                                                   const float* __restrict__ x,
                                                   unsigned* __restrict__ oh,
                                                   uint2* __restrict__ hig) {
    __shared__ float ch[2][PDW];
    __shared__ float s4[4][PDW];
    __shared__ float wtot[4];
    int t = threadIdx.x;
    size_t g = (size_t)blockIdx.x * ROWSZ;
    const uint4* vrow = (const uint4*)(vsum + (size_t)blockIdx.x * STR2);
    uint4 u = vrow[t];
    {
        float2 p0 = up2(u.x), p1 = up2(u.y), p2 = up2(u.z), p3 = up2(u.w);
        int w = 4 * t;
        ch[0][PD(w + 0)] = p0.x; ch[1][PD(w + 0)] = p0.y;
        ch[0][PD(w + 1)] = p1.x; ch[1][PD(w + 1)] = p1.y;
        ch[0][PD(w + 2)] = p2.x; ch[1][PD(w + 2)] = p2.y;
        ch[0][PD(w + 3)] = p3.x; ch[1][PD(w + 3)] = p3.y;
    }
    __syncthreads();
    {
        int c = t >> 7, j = t & 127, base = j * 8;
        float v[8]; float run = 0.f;
        #pragma unroll
        for (int i = 0; i < 8; ++i) { run += ch[c][PD(base + i)]; v[i] = run; }
        float incl = wave_incl_scan(run);
        int wid = t >> 6;
        if ((t & 63) == 63) wtot[wid] = incl;
        __syncthreads();
        float off = incl - run;
        if (wid & 1) off += wtot[wid - 1];
        #pragma unroll
        for (int i = 0; i < 8; ++i) ch[c][PD(base + i)] = off + v[i];
    }
    __syncthreads();
    const float4* xrow = (const float4*)(x + g);
    uint2* ohrow = (uint2*)(oh + (size_t)blockIdx.x * STR2);
    #pragma unroll
    for (int i = 0; i < 2; ++i) {
        int jj = t + 256 * i;
        int w0 = 2 * jj, w1 = 2 * jj + 1;
        int hi0 = w0 + RAD; if (hi0 > WW - 1) hi0 = WW - 1;
        int hi1 = w1 + RAD; if (hi1 > WW - 1) hi1 = WW - 1;
        int lo0 = w0 - RAD - 1, lo1 = w1 - RAD - 1;
        float s00 = ch[0][PD(hi0)], s10 = ch[1][PD(hi0)];
        if (lo0 >= 0) { s00 -= ch[0][PD(lo0)]; s10 -= ch[1][PD(lo0)]; }
        float s01 = ch[0][PD(hi1)], s11 = ch[1][PD(hi1)];
        if (lo1 >= 0) { s01 -= ch[0][PD(lo1)]; s11 -= ch[1][PD(lo1)]; }
        float4 xv = xrow[jj];
        float4 o;
        o.x = xv.x - SCALEV * s00; o.y = xv.y - SCALEV * s10;
        o.z = xv.z - SCALEV * s01; o.w = xv.w - SCALEV * s11;
        ohrow[jj] = make_uint2(pkh(o.x, o.y), pkh(o.z, o.w));
        s4[0][PD(w0)] = o.x;       s4[1][PD(w0)] = o.y;
        s4[0][PD(w1)] = o.z;       s4[1][PD(w1)] = o.w;
        s4[2][PD(w0)] = o.x * o.x; s4[3][PD(w0)] = o.y * o.y;
        s4[2][PD(w1)] = o.z * o.z; s4[3][PD(w1)] = o.w * o.w;
    }
    __syncthreads();
    {
        int a = t >> 6, j = t & 63, base = j * 16;
        float v[16]; float run = 0.f;
        #pragma unroll
        for (int i = 0; i < 16; ++i) { run += s4[a][PD(base + i)]; v[i] = run; }
        float incl = wave_incl_scan(run);
        float off = incl - run;
        #pragma unroll
        for (int i = 0; i < 16; ++i) s4[a][PD(base + i)] = off + v[i];
    }
    __syncthreads();
    uint4* hirow = (uint4*)(hig + (size_t)blockIdx.x * STR2);
    #pragma unroll
    for (int i = 0; i < 2; ++i) {
        int jj = t + 256 * i;
        int w0 = 2 * jj, w1 = 2 * jj + 1;
        int hi0 = w0 + RAD; if (hi0 > WW - 1) hi0 = WW - 1;
        int hi1 = w1 + RAD; if (hi1 > WW - 1) hi1 = WW - 1;
        int lo0 = w0 - RAD - 1, lo1 = w1 - RAD - 1;
        float a00 = s4[0][PD(hi0)], a10 = s4[1][PD(hi0)];
        float q00 = s4[2][PD(hi0)], q10 = s4[3][PD(hi0)];
        if (lo0 >= 0) {
            a00 -= s4[0][PD(lo0)]; a10 -= s4[1][PD(lo0)];
            q00 -= s4[2][PD(lo0)]; q10 -= s4[3][PD(lo0)];
        }
        float a01 = s4[0][PD(hi1)], a11 = s4[1][PD(hi1)];
        float q01 = s4[2][PD(hi1)], q11 = s4[3][PD(hi1)];
        if (lo1 >= 0) {
            a01 -= s4[0][PD(lo1)]; a11 -= s4[1][PD(lo1)];
            q01 -= s4[2][PD(lo1)]; q11 -= s4[3][PD(lo1)];
        }
        hirow[jj] = make_uint4(pk2(a00, a10), pk2(q00, q10),
                               pk2(a01, a11), pk2(q01, q11));
    }
}

// ---------------------------------------------------------------------------
// K3': vertical 61-box of interleaved HI (bf16) + finalize y = o/(sqrt(var)+eps).
// 8B lanes (1 pixel/thread), V32 -> 1024 blocks; fp16 numerator from OH;
// fp32 write-once to d_out; fast sqrt/rcp; double-buffered 8-row pipeline.
__global__ __launch_bounds__(256) void vfinal_kernel(const uint2* __restrict__ hi,
                                                     const unsigned* __restrict__ oh,
                                                     float* __restrict__ fout) {
    int tid = blockIdx.x * 256 + threadIdx.x;
    int col = tid & (NCOL2 - 1);
    int seg = tid >> 13;
    int n = col >> 10;
    int w2 = col & (STR2 - 1);
    const uint2* pp = hi + (size_t)n * (size_t)HH * STR2 + w2;
    const unsigned* po = oh + (size_t)n * (IMGSZ / 2) + w2;
    float2* fo = (float2*)(fout + (size_t)n * IMGSZ) + w2;
    int h0 = seg * VSEGH;
    float2 S1 = make_float2(0.f, 0.f), S2 = make_float2(0.f, 0.f);
    int lo = h0 - RAD; if (lo < 0) lo = 0;
    int hiend = h0 + RAD; if (hiend > HH) hiend = HH;
    int h = lo;
    for (; h + 8 <= hiend; h += 8) {
        uint2 A[8];
        #pragma unroll
        for (int i = 0; i < 8; ++i) A[i] = pp[(h + i) * STR2];
        __builtin_amdgcn_sched_barrier(0);
        #pragma unroll
        for (int i = 0; i < 8; ++i) {
            S1 = f2add(S1, up2(A[i].x));
            S2 = f2add(S2, up2(A[i].y));
        }
    }
    for (; h < hiend; ++h) {
        uint2 v = pp[h * STR2];
        S1 = f2add(S1, up2(v.x));
        S2 = f2add(S2, up2(v.y));
    }

#define VF_ROW(Ai, Oi, Ti, ro) { \
    S1 = f2add(S1, up2((Ai).x)); S2 = f2add(S2, up2((Ai).y)); \
    float2 o = uph(Oi); \
    float2 yv; \
    yv.x = o.x * rcp_f(sqrt_f(fmaxf(SCALEV * S2.x - (SCALEV * S1.x) * (SCALEV * S1.x), 0.f)) + EPSV); \
    yv.y = o.y * rcp_f(sqrt_f(fmaxf(SCALEV * S2.y - (SCALEV * S1.y) * (SCALEV * S1.y), 0.f)) + EPSV); \
    oq[(ro) * STR2] = yv; \
    S1 = f2sub(S1, up2((Ti).x)); S2 = f2sub(S2, up2((Ti).y)); \
}

    if (h0 >= RAD && h0 + VSEGH + RAD <= HH) {   // interior (bounds-based)
        const uint2* lp = pp + (h0 + RAD) * STR2;
        const uint2* tp = pp + (h0 - RAD) * STR2;
        const unsigned* orp = po + (size_t)h0 * STR2;
        float2* oq = fo + (size_t)h0 * STR2;
        uint2 LA[8], TA[8], LB[8], TB[8];
        unsigned OA[8], OB[8];
#define VF_LOAD(Lx, Tx, Ox, r) { \
        _Pragma("unroll") for (int i = 0; i < 8; ++i) Lx[i] = lp[((r) + i) * STR2]; \
        _Pragma("unroll") for (int i = 0; i < 8; ++i) Tx[i] = tp[((r) + i) * STR2]; \
        _Pragma("unroll") for (int i = 0; i < 8; ++i) Ox[i] = orp[((r) + i) * STR2]; \
        __builtin_amdgcn_sched_barrier(0); }
#define VF_CONS(Lx, Tx, Ox, r) { \
        _Pragma("unroll") for (int i = 0; i < 8; ++i) VF_ROW(Lx[i], Ox[i], Tx[i], (r) + i) }
        VF_LOAD(LA, TA, OA, 0)
        VF_LOAD(LB, TB, OB, 8)
        VF_CONS(LA, TA, OA, 0)
        VF_LOAD(LA, TA, OA, 16)
        VF_CONS(LB, TB, OB, 8)
        VF_LOAD(LB, TB, OB, 24)
        VF_CONS(LA, TA, OA, 16)
        VF_CONS(LB, TB, OB, 24)
#undef VF_LOAD
#undef VF_CONS
    } else {
        const uint2 Z2u = make_uint2(0u, 0u);
        float2* oq = fo;   // absolute row index used below
        for (int ho = h0; ho < h0 + VSEGH; ho += 4) {
            uint2 a[4], b[4];
            unsigned O[4];
            #pragma unroll
            for (int i = 0; i < 4; ++i) {
                int ha = ho + i + RAD;
                a[i] = (ha < HH) ? pp[ha * STR2] : Z2u;
            }
            #pragma unroll
            for (int i = 0; i < 4; ++i) {
                int hb = ho + i - RAD;
                b[i] = (hb >= 0) ? pp[hb * STR2] : Z2u;
            }
            #pragma unroll
            for (int i = 0; i < 4; ++i) O[i] = po[(size_t)(ho + i) * STR2];
            #pragma unroll
            for (int i = 0; i < 4; ++i) {
                VF_ROW(a[i], O[i], b[i], (size_t)(ho + i))
            }
        }
        (void)oq;
    }
#undef VF_ROW
}

extern "C" void kernel_launch(void* const* d_in, const int* in_sizes, int n_in,
                              void* d_out, int out_size, void* d_ws, size_t ws_size,
                              hipStream_t stream) {
    const float* x = (const float*)d_in[0];
    float* out = (float*)d_out;
    unsigned* V1 = (unsigned*)d_ws;                       // 32 MB bf16 vbox(x); later ALIASED as fp16 OH
    unsigned* OH = V1;                                    // fp16 numerator plane (same rows, same size)
    uint2* HI = (uint2*)(V1 + (size_t)NB * IMGSZ / 2);    // 64 MB interleaved Hbox(out), Hbox(out^2)

    int vgrid = (NCOL2 * VNSEG) / 256;                    // 1024 blocks
    vbox_kernel<<<vgrid, 256, 0, stream>>>(x, V1);
    hmid_kernel<<<NB * HH, 256, 0, stream>>>(V1, x, OH, HI);
    vfinal_kernel<<<vgrid, 256, 0, stream>>>(HI, OH, out);
}

// Round 10
// 206.736 us; speedup vs baseline: 1.0187x; 1.0187x over previous
//
#include <hip/hip_runtime.h>
#include <hip/hip_fp16.h>
#include <math.h>

// Problem constants (fixed by setup_inputs): x is (8,1024,1024,2) fp32, k=61
#define NB 8
#define HH 1024
#define WW 1024
#define RAD 30
#define KS 61
#define ROWSZ 2048             /* floats per row (1024 px x 2 ch) */
#define IMGSZ (HH * ROWSZ)
#define STR2 1024              /* pixel stride per row (uint2/unsigned planes) */
#define STR4 512               /* uint4/float4 per row */
#define NCOL4 (NB * STR4)      /* 4096 wide-lane columns */
#define VSEGH 32               /* 512 blocks at 16B lanes */
#define VNSEG (HH / VSEGH)     /* 32 */
#define EPSV 1e-7f
#define SCALEV (1.0f / (float)(KS * KS * 2))
#define PDW (WW + WW / 8)
#define PD(i) ((i) + ((i) >> 3))

// ---- bf16 pack/unpack (manual, round-to-nearest-even) ----------------------
__device__ __forceinline__ unsigned bf16_rn(float f) {
    unsigned u = __float_as_uint(f);
    return (u + 0x7FFFu + ((u >> 16) & 1u)) >> 16;
}
__device__ __forceinline__ unsigned pk2(float a, float b) {
    return bf16_rn(a) | (bf16_rn(b) << 16);
}
__device__ __forceinline__ float2 up2(unsigned u) {
    return make_float2(__uint_as_float(u << 16),
                       __uint_as_float(u & 0xFFFF0000u));
}
// ---- fp16 pack/unpack (numerator plane) ------------------------------------
__device__ __forceinline__ unsigned pkh(float a, float b) {
    __half2 h = __floats2half2_rn(a, b);
    return *reinterpret_cast<unsigned*>(&h);
}
__device__ __forceinline__ float2 uph(unsigned u) {
    __half2 h = *reinterpret_cast<__half2*>(&u);
    return __half22float2(h);
}
__device__ __forceinline__ float2 f2add(float2 a, float2 b) {
    return make_float2(a.x + b.x, a.y + b.y);
}
__device__ __forceinline__ float2 f2sub(float2 a, float2 b) {
    return make_float2(a.x - b.x, a.y - b.y);
}
// fast single-instruction transcendentals (v_sqrt_f32 / v_rcp_f32, ~1 ulp)
__device__ __forceinline__ float sqrt_f(float x) { return __builtin_amdgcn_sqrtf(x); }
__device__ __forceinline__ float rcp_f(float x)  { return __builtin_amdgcn_rcpf(x); }

// ---------------------------------------------------------------------------
// K1: vertical 61-tap box-sum of x -> V1 (bf16-packed). 16B lanes (2 pixels),
// VSEGH=32 (512 blocks). TRIPLE-buffered interior (48 loads / 768B per lane
// in flight) + 16-deep prologue batches: deeper MLP per wave to amortize the
// ~900cy HBM latency that pins the row-step rate.
__global__ __launch_bounds__(256) void vbox_kernel(const float* __restrict__ in,
                                                   unsigned* __restrict__ out) {
    int tid = blockIdx.x * 256 + threadIdx.x;
    int col = tid & (NCOL4 - 1);
    int seg = tid >> 12;
    int n = col >> 9;
    int c = col & (STR4 - 1);
    const float4* ip = (const float4*)(in + (size_t)n * IMGSZ) + c;
    uint2* op = (uint2*)(out + (size_t)n * (IMGSZ / 2)) + c;
    int h0 = seg * VSEGH;
    float4 S = make_float4(0.f, 0.f, 0.f, 0.f);
    int lo = h0 - RAD; if (lo < 0) lo = 0;
    int hiend = h0 + RAD; if (hiend > HH) hiend = HH;
    int h = lo;
    for (; h + 16 <= hiend; h += 16) {
        float4 W[16];
        #pragma unroll
        for (int i = 0; i < 16; ++i) W[i] = ip[(h + i) * STR4];
        __builtin_amdgcn_sched_barrier(0);
        #pragma unroll
        for (int i = 0; i < 16; ++i) {
            S.x += W[i].x; S.y += W[i].y; S.z += W[i].z; S.w += W[i].w;
        }
    }
    for (; h + 8 <= hiend; h += 8) {
        float4 W[8];
        #pragma unroll
        for (int i = 0; i < 8; ++i) W[i] = ip[(h + i) * STR4];
        __builtin_amdgcn_sched_barrier(0);
        #pragma unroll
        for (int i = 0; i < 8; ++i) {
            S.x += W[i].x; S.y += W[i].y; S.z += W[i].z; S.w += W[i].w;
        }
    }
    for (; h < hiend; ++h) {
        float4 w = ip[h * STR4];
        S.x += w.x; S.y += w.y; S.z += w.z; S.w += w.w;
    }

    if (h0 >= RAD && h0 + VSEGH + RAD <= HH) {   // interior (bounds-based)
        const float4* lp = ip + (h0 + RAD) * STR4;
        const float4* tp = ip + (h0 - RAD) * STR4;
        uint2* opp = op + (size_t)h0 * STR4;
        float4 LA[8], TA[8], LB[8], TB[8], LC[8], TC[8];
#define VB_LOAD(Lx, Tx, r) { \
        _Pragma("unroll") for (int i = 0; i < 8; ++i) Lx[i] = lp[((r) + i) * STR4]; \
        _Pragma("unroll") for (int i = 0; i < 8; ++i) Tx[i] = tp[((r) + i) * STR4]; \
        __builtin_amdgcn_sched_barrier(0); }
#define VB_CONS(Lx, Tx, r) { \
        _Pragma("unroll") for (int i = 0; i < 8; ++i) { \
            S.x += Lx[i].x; S.y += Lx[i].y; S.z += Lx[i].z; S.w += Lx[i].w; \
            opp[((r) + i) * STR4] = make_uint2(pk2(S.x, S.y), pk2(S.z, S.w)); \
            S.x -= Tx[i].x; S.y -= Tx[i].y; S.z -= Tx[i].z; S.w -= Tx[i].w; } }
        VB_LOAD(LA, TA, 0)
        VB_LOAD(LB, TB, 8)
        VB_LOAD(LC, TC, 16)
        VB_CONS(LA, TA, 0)
        VB_LOAD(LA, TA, 24)
        VB_CONS(LB, TB, 8)
        VB_CONS(LC, TC, 16)
        VB_CONS(LA, TA, 24)
#undef VB_LOAD
#undef VB_CONS
    } else {
        const float4 Z = make_float4(0.f, 0.f, 0.f, 0.f);
        for (int ho = h0; ho < h0 + VSEGH; ho += 4) {
            float4 a[4], b[4];
            #pragma unroll
            for (int i = 0; i < 4; ++i) {
                int ha = ho + i + RAD;
                a[i] = (ha < HH) ? ip[ha * STR4] : Z;
            }
            #pragma unroll
            for (int i = 0; i < 4; ++i) {
                int hb = ho + i - RAD;
                b[i] = (hb >= 0) ? ip[hb * STR4] : Z;
            }
            #pragma unroll
            for (int i = 0; i < 4; ++i) {
                S.x += a[i].x; S.y += a[i].y; S.z += a[i].z; S.w += a[i].w;
                op[(size_t)(ho + i) * STR4] = make_uint2(pk2(S.x, S.y), pk2(S.z, S.w));
                S.x -= b[i].x; S.y -= b[i].y; S.z -= b[i].z; S.w -= b[i].w;
            }
        }
    }
}

__device__ inline float wave_incl_scan(float v) {
    int lane = threadIdx.x & 63;
    #pragma unroll
    for (int d = 1; d < 64; d <<= 1) {
        float o = __shfl_up(v, d, 64);
        if (lane >= d) v += o;
    }
    return v;
}

// ---------------------------------------------------------------------------
// K2': fused middle kernel, one block per row (r8-proven).
//   phase 1: prefix-scan V1 row -> horizontal box -> m; numerator out = x - m,
//            written fp16 into OH (aliases V1; same-block RAW->WAR, race-free).
//   phase 2: prefix-scan out, out^2 (LDS) -> 61-tap horizontal box sums,
//            written interleaved uint2{h1,h2} per pixel (bf16x2 each).
__global__ __launch_bounds__(256) void hmid_kernel(const unsigned* __restrict__ vsum,
                                                   const float* __restrict__ x,
                                                   unsigned* __restrict__ oh,
                                                   uint2* __restrict__ hig) {
    __shared__ float ch[2][PDW];
    __shared__ float s4[4][PDW];
    __shared__ float wtot[4];
    int t = threadIdx.x;
    size_t g = (size_t)blockIdx.x * ROWSZ;
    const uint4* vrow = (const uint4*)(vsum + (size_t)blockIdx.x * STR2);
    uint4 u = vrow[t];
    {
        float2 p0 = up2(u.x), p1 = up2(u.y), p2 = up2(u.z), p3 = up2(u.w);
        int w = 4 * t;
        ch[0][PD(w + 0)] = p0.x; ch[1][PD(w + 0)] = p0.y;
        ch[0][PD(w + 1)] = p1.x; ch[1][PD(w + 1)] = p1.y;
        ch[0][PD(w + 2)] = p2.x; ch[1][PD(w + 2)] = p2.y;
        ch[0][PD(w + 3)] = p3.x; ch[1][PD(w + 3)] = p3.y;
    }
    __syncthreads();
    {
        int c = t >> 7, j = t & 127, base = j * 8;
        float v[8]; float run = 0.f;
        #pragma unroll
        for (int i = 0; i < 8; ++i) { run += ch[c][PD(base + i)]; v[i] = run; }
        float incl = wave_incl_scan(run);
        int wid = t >> 6;
        if ((t & 63) == 63) wtot[wid] = incl;
        __syncthreads();
        float off = incl - run;
        if (wid & 1) off += wtot[wid - 1];
        #pragma unroll
        for (int i = 0; i < 8; ++i) ch[c][PD(base + i)] = off + v[i];
    }
    __syncthreads();
    const float4* xrow = (const float4*)(x + g);
    uint2* ohrow = (uint2*)(oh + (size_t)blockIdx.x * STR2);
    #pragma unroll
    for (int i = 0; i < 2; ++i) {
        int jj = t + 256 * i;
        int w0 = 2 * jj, w1 = 2 * jj + 1;
        int hi0 = w0 + RAD; if (hi0 > WW - 1) hi0 = WW - 1;
        int hi1 = w1 + RAD; if (hi1 > WW - 1) hi1 = WW - 1;
        int lo0 = w0 - RAD - 1, lo1 = w1 - RAD - 1;
        float s00 = ch[0][PD(hi0)], s10 = ch[1][PD(hi0)];
        if (lo0 >= 0) { s00 -= ch[0][PD(lo0)]; s10 -= ch[1][PD(lo0)]; }
        float s01 = ch[0][PD(hi1)], s11 = ch[1][PD(hi1)];
        if (lo1 >= 0) { s01 -= ch[0][PD(lo1)]; s11 -= ch[1][PD(lo1)]; }
        float4 xv = xrow[jj];
        float4 o;
        o.x = xv.x - SCALEV * s00; o.y = xv.y - SCALEV * s10;
        o.z = xv.z - SCALEV * s01; o.w = xv.w - SCALEV * s11;
        ohrow[jj] = make_uint2(pkh(o.x, o.y), pkh(o.z, o.w));
        s4[0][PD(w0)] = o.x;       s4[1][PD(w0)] = o.y;
        s4[0][PD(w1)] = o.z;       s4[1][PD(w1)] = o.w;
        s4[2][PD(w0)] = o.x * o.x; s4[3][PD(w0)] = o.y * o.y;
        s4[2][PD(w1)] = o.z * o.z; s4[3][PD(w1)] = o.w * o.w;
    }
    __syncthreads();
    {
        int a = t >> 6, j = t & 63, base = j * 16;
        float v[16]; float run = 0.f;
        #pragma unroll
        for (int i = 0; i < 16; ++i) { run += s4[a][PD(base + i)]; v[i] = run; }
        float incl = wave_incl_scan(run);
        float off = incl - run;
        #pragma unroll
        for (int i = 0; i < 16; ++i) s4[a][PD(base + i)] = off + v[i];
    }
    __syncthreads();
    uint4* hirow = (uint4*)(hig + (size_t)blockIdx.x * STR2);
    #pragma unroll
    for (int i = 0; i < 2; ++i) {
        int jj = t + 256 * i;
        int w0 = 2 * jj, w1 = 2 * jj + 1;
        int hi0 = w0 + RAD; if (hi0 > WW - 1) hi0 = WW - 1;
        int hi1 = w1 + RAD; if (hi1 > WW - 1) hi1 = WW - 1;
        int lo0 = w0 - RAD - 1, lo1 = w1 - RAD - 1;
        float a00 = s4[0][PD(hi0)], a10 = s4[1][PD(hi0)];
        float q00 = s4[2][PD(hi0)], q10 = s4[3][PD(hi0)];
        if (lo0 >= 0) {
            a00 -= s4[0][PD(lo0)]; a10 -= s4[1][PD(lo0)];
            q00 -= s4[2][PD(lo0)]; q10 -= s4[3][PD(lo0)];
        }
        float a01 = s4[0][PD(hi1)], a11 = s4[1][PD(hi1)];
        float q01 = s4[2][PD(hi1)], q11 = s4[3][PD(hi1)];
        if (lo1 >= 0) {
            a01 -= s4[0][PD(lo1)]; a11 -= s4[1][PD(lo1)];
            q01 -= s4[2][PD(lo1)]; q11 -= s4[3][PD(lo1)];
        }
        hirow[jj] = make_uint4(pk2(a00, a10), pk2(q00, q10),
                               pk2(a01, a11), pk2(q01, q11));
    }
}

// ---------------------------------------------------------------------------
// K3': vertical 61-box of interleaved HI (bf16) + finalize y = o/(sqrt(var)+eps).
// r8-proven config: 16B lanes, V32 (512 blocks), fp16 numerator from OH,
// fp32 write-once to d_out, fast sqrt/rcp, double-buffered 8-row pipeline.
__global__ __launch_bounds__(256) void vfinal_kernel(const uint2* __restrict__ hi,
                                                     const unsigned* __restrict__ oh,
                                                     float* __restrict__ fout) {
    int tid = blockIdx.x * 256 + threadIdx.x;
    int col = tid & (NCOL4 - 1);
    int seg = tid >> 12;
    int n = col >> 9;
    int c = col & (STR4 - 1);
    const uint4* pp = (const uint4*)(hi + (size_t)n * (size_t)HH * STR2) + c;
    const uint2* po = (const uint2*)(oh + (size_t)n * (IMGSZ / 2)) + c;
    float4* fo = (float4*)(fout + (size_t)n * IMGSZ) + c;
    int h0 = seg * VSEGH;
    float2 S1a = make_float2(0.f, 0.f), S2a = make_float2(0.f, 0.f);
    float2 S1b = make_float2(0.f, 0.f), S2b = make_float2(0.f, 0.f);
    int lo = h0 - RAD; if (lo < 0) lo = 0;
    int hiend = h0 + RAD; if (hiend > HH) hiend = HH;
    int h = lo;
    for (; h + 8 <= hiend; h += 8) {
        uint4 A[8];
        #pragma unroll
        for (int i = 0; i < 8; ++i) A[i] = pp[(h + i) * STR4];
        __builtin_amdgcn_sched_barrier(0);
        #pragma unroll
        for (int i = 0; i < 8; ++i) {
            S1a = f2add(S1a, up2(A[i].x)); S2a = f2add(S2a, up2(A[i].y));
            S1b = f2add(S1b, up2(A[i].z)); S2b = f2add(S2b, up2(A[i].w));
        }
    }
    for (; h < hiend; ++h) {
        uint4 v = pp[h * STR4];
        S1a = f2add(S1a, up2(v.x)); S2a = f2add(S2a, up2(v.y));
        S1b = f2add(S1b, up2(v.z)); S2b = f2add(S2b, up2(v.w));
    }

#define VF_ROW(Ai, Oi, Ti, ro) { \
    S1a = f2add(S1a, up2((Ai).x)); S2a = f2add(S2a, up2((Ai).y)); \
    S1b = f2add(S1b, up2((Ai).z)); S2b = f2add(S2b, up2((Ai).w)); \
    float2 oA = uph((Oi).x), oB = uph((Oi).y); \
    float4 yv; \
    yv.x = oA.x * rcp_f(sqrt_f(fmaxf(SCALEV * S2a.x - (SCALEV * S1a.x) * (SCALEV * S1a.x), 0.f)) + EPSV); \
    yv.y = oA.y * rcp_f(sqrt_f(fmaxf(SCALEV * S2a.y - (SCALEV * S1a.y) * (SCALEV * S1a.y), 0.f)) + EPSV); \
    yv.z = oB.x * rcp_f(sqrt_f(fmaxf(SCALEV * S2b.x - (SCALEV * S1b.x) * (SCALEV * S1b.x), 0.f)) + EPSV); \
    yv.w = oB.y * rcp_f(sqrt_f(fmaxf(SCALEV * S2b.y - (SCALEV * S1b.y) * (SCALEV * S1b.y), 0.f)) + EPSV); \
    oq[(ro) * STR4] = yv; \
    S1a = f2sub(S1a, up2((Ti).x)); S2a = f2sub(S2a, up2((Ti).y)); \
    S1b = f2sub(S1b, up2((Ti).z)); S2b = f2sub(S2b, up2((Ti).w)); \
}

    if (h0 >= RAD && h0 + VSEGH + RAD <= HH) {   // interior (bounds-based)
        const uint4* lp = pp + (h0 + RAD) * STR4;
        const uint4* tp = pp + (h0 - RAD) * STR4;
        const uint2* orp = po + (size_t)h0 * STR4;
        float4* oq = fo + (size_t)h0 * STR4;
        uint4 LA[8], TA[8], LB[8], TB[8];
        uint2 OA[8], OB[8];
#define VF_LOAD(Lx, Tx, Ox, r) { \
        _Pragma("unroll") for (int i = 0; i < 8; ++i) Lx[i] = lp[((r) + i) * STR4]; \
        _Pragma("unroll") for (int i = 0; i < 8; ++i) Tx[i] = tp[((r) + i) * STR4]; \
        _Pragma("unroll") for (int i = 0; i < 8; ++i) Ox[i] = orp[((r) + i) * STR4]; \
        __builtin_amdgcn_sched_barrier(0); }
#define VF_CONS(Lx, Tx, Ox, r) { \
        _Pragma("unroll") for (int i = 0; i < 8; ++i) VF_ROW(Lx[i], Ox[i], Tx[i], (r) + i) }
        VF_LOAD(LA, TA, OA, 0)
        VF_LOAD(LB, TB, OB, 8)
        VF_CONS(LA, TA, OA, 0)
        VF_LOAD(LA, TA, OA, 16)
        VF_CONS(LB, TB, OB, 8)
        VF_LOAD(LB, TB, OB, 24)
        VF_CONS(LA, TA, OA, 16)
        VF_CONS(LB, TB, OB, 24)
#undef VF_LOAD
#undef VF_CONS
    } else {
        const uint4 Z4 = make_uint4(0u, 0u, 0u, 0u);
        float4* oq = fo;   // absolute row index used below
        for (int ho = h0; ho < h0 + VSEGH; ho += 4) {
            uint4 a[4], b[4];
            uint2 O[4];
            #pragma unroll
            for (int i = 0; i < 4; ++i) {
                int ha = ho + i + RAD;
                a[i] = (ha < HH) ? pp[ha * STR4] : Z4;
            }
            #pragma unroll
            for (int i = 0; i < 4; ++i) {
                int hb = ho + i - RAD;
                b[i] = (hb >= 0) ? pp[hb * STR4] : Z4;
            }
            #pragma unroll
            for (int i = 0; i < 4; ++i) O[i] = po[(size_t)(ho + i) * STR4];
            #pragma unroll
            for (int i = 0; i < 4; ++i) {
                VF_ROW(a[i], O[i], b[i], (size_t)(ho + i))
            }
        }
        (void)oq;
    }
#undef VF_ROW
}

extern "C" void kernel_launch(void* const* d_in, const int* in_sizes, int n_in,
                              void* d_out, int out_size, void* d_ws, size_t ws_size,
                              hipStream_t stream) {
    const float* x = (const float*)d_in[0];
    float* out = (float*)d_out;
    unsigned* V1 = (unsigned*)d_ws;                       // 32 MB bf16 vbox(x); later ALIASED as fp16 OH
    unsigned* OH = V1;                                    // fp16 numerator plane (same rows, same size)
    uint2* HI = (uint2*)(V1 + (size_t)NB * IMGSZ / 2);    // 64 MB interleaved Hbox(out), Hbox(out^2)

    int vgrid = (NCOL4 * VNSEG) / 256;                    // 512 blocks
    vbox_kernel<<<vgrid, 256, 0, stream>>>(x, V1);
    hmid_kernel<<<NB * HH, 256, 0, stream>>>(V1, x, OH, HI);
    vfinal_kernel<<<vgrid, 256, 0, stream>>>(HI, OH, out);
}

// Round 11
// 205.161 us; speedup vs baseline: 1.0265x; 1.0077x over previous
//
#include <hip/hip_runtime.h>
#include <hip/hip_fp16.h>
#include <math.h>

// Problem constants (fixed by setup_inputs): x is (8,1024,1024,2) fp32, k=61
#define NB 8
#define HH 1024
#define WW 1024
#define RAD 30
#define KS 61
#define ROWSZ 2048             /* floats per row (1024 px x 2 ch) */
#define IMGSZ (HH * ROWSZ)
#define STR2 1024              /* pixel stride per row (uint2/unsigned planes) */
#define STR4 512               /* uint4/float4 per row */
#define NCOL4 (NB * STR4)      /* 4096 wide-lane columns */
#define VSEGH 32               /* 512 blocks at 16B lanes */
#define VNSEG (HH / VSEGH)     /* 32 */
#define EPSV 1e-7f
#define SCALEV (1.0f / (float)(KS * KS * 2))
#define PDW (WW + WW / 8)
#define PD(i) ((i) + ((i) >> 3))

// Real memory fence: unlike sched_barrier(0), an asm with a "memory" clobber
// may write memory at IR level, so LLVM cannot sink the (read-only) batch
// loads across it into the consume loop. This is what actually pins the
// load batches in flight (sched_barrier left VGPR_Count at 48 => collapsed).
#define MEMFENCE asm volatile("" ::: "memory")

// ---- bf16 pack/unpack (manual, round-to-nearest-even) ----------------------
__device__ __forceinline__ unsigned bf16_rn(float f) {
    unsigned u = __float_as_uint(f);
    return (u + 0x7FFFu + ((u >> 16) & 1u)) >> 16;
}
__device__ __forceinline__ unsigned pk2(float a, float b) {
    return bf16_rn(a) | (bf16_rn(b) << 16);
}
__device__ __forceinline__ float2 up2(unsigned u) {
    return make_float2(__uint_as_float(u << 16),
                       __uint_as_float(u & 0xFFFF0000u));
}
// ---- fp16 pack/unpack (numerator plane) ------------------------------------
__device__ __forceinline__ unsigned pkh(float a, float b) {
    __half2 h = __floats2half2_rn(a, b);
    return *reinterpret_cast<unsigned*>(&h);
}
__device__ __forceinline__ float2 uph(unsigned u) {
    __half2 h = *reinterpret_cast<__half2*>(&u);
    return __half22float2(h);
}
__device__ __forceinline__ float2 f2add(float2 a, float2 b) {
    return make_float2(a.x + b.x, a.y + b.y);
}
__device__ __forceinline__ float2 f2sub(float2 a, float2 b) {
    return make_float2(a.x - b.x, a.y - b.y);
}
// fast single-instruction transcendentals (v_sqrt_f32 / v_rcp_f32, ~1 ulp)
__device__ __forceinline__ float sqrt_f(float x) { return __builtin_amdgcn_sqrtf(x); }
__device__ __forceinline__ float rcp_f(float x)  { return __builtin_amdgcn_rcpf(x); }

// ---------------------------------------------------------------------------
// K1: vertical 61-tap box-sum of x -> V1 (bf16-packed). 16B lanes (2 pixels),
// VSEGH=32 (512 blocks). Triple-buffered interior with REAL memory fences so
// 48 loads (768B/lane) are genuinely in flight. launch_bounds(256,2): allow
// up to 256 VGPR at 2 waves/SIMD (grid caps occupancy at 8 waves/CU anyway).
__global__ __launch_bounds__(256, 2) void vbox_kernel(const float* __restrict__ in,
                                                      unsigned* __restrict__ out) {
    int tid = blockIdx.x * 256 + threadIdx.x;
    int col = tid & (NCOL4 - 1);
    int seg = tid >> 12;
    int n = col >> 9;
    int c = col & (STR4 - 1);
    const float4* ip = (const float4*)(in + (size_t)n * IMGSZ) + c;
    uint2* op = (uint2*)(out + (size_t)n * (IMGSZ / 2)) + c;
    int h0 = seg * VSEGH;
    float4 S = make_float4(0.f, 0.f, 0.f, 0.f);
    int lo = h0 - RAD; if (lo < 0) lo = 0;
    int hiend = h0 + RAD; if (hiend > HH) hiend = HH;
    int h = lo;
    for (; h + 16 <= hiend; h += 16) {
        float4 W[16];
        #pragma unroll
        for (int i = 0; i < 16; ++i) W[i] = ip[(h + i) * STR4];
        MEMFENCE;
        #pragma unroll
        for (int i = 0; i < 16; ++i) {
            S.x += W[i].x; S.y += W[i].y; S.z += W[i].z; S.w += W[i].w;
        }
    }
    for (; h + 8 <= hiend; h += 8) {
        float4 W[8];
        #pragma unroll
        for (int i = 0; i < 8; ++i) W[i] = ip[(h + i) * STR4];
        MEMFENCE;
        #pragma unroll
        for (int i = 0; i < 8; ++i) {
            S.x += W[i].x; S.y += W[i].y; S.z += W[i].z; S.w += W[i].w;
        }
    }
    for (; h < hiend; ++h) {
        float4 w = ip[h * STR4];
        S.x += w.x; S.y += w.y; S.z += w.z; S.w += w.w;
    }

    if (h0 >= RAD && h0 + VSEGH + RAD <= HH) {   // interior (bounds-based)
        const float4* lp = ip + (h0 + RAD) * STR4;
        const float4* tp = ip + (h0 - RAD) * STR4;
        uint2* opp = op + (size_t)h0 * STR4;
        float4 LA[8], TA[8], LB[8], TB[8], LC[8], TC[8];
#define VB_LOAD(Lx, Tx, r) { \
        _Pragma("unroll") for (int i = 0; i < 8; ++i) Lx[i] = lp[((r) + i) * STR4]; \
        _Pragma("unroll") for (int i = 0; i < 8; ++i) Tx[i] = tp[((r) + i) * STR4]; \
        MEMFENCE; }
#define VB_CONS(Lx, Tx, r) { \
        _Pragma("unroll") for (int i = 0; i < 8; ++i) { \
            S.x += Lx[i].x; S.y += Lx[i].y; S.z += Lx[i].z; S.w += Lx[i].w; \
            opp[((r) + i) * STR4] = make_uint2(pk2(S.x, S.y), pk2(S.z, S.w)); \
            S.x -= Tx[i].x; S.y -= Tx[i].y; S.z -= Tx[i].z; S.w -= Tx[i].w; } }
        VB_LOAD(LA, TA, 0)
        VB_LOAD(LB, TB, 8)
        VB_LOAD(LC, TC, 16)
        VB_CONS(LA, TA, 0)
        VB_LOAD(LA, TA, 24)
        VB_CONS(LB, TB, 8)
        VB_CONS(LC, TC, 16)
        VB_CONS(LA, TA, 24)
#undef VB_LOAD
#undef VB_CONS
    } else {
        const float4 Z = make_float4(0.f, 0.f, 0.f, 0.f);
        for (int ho = h0; ho < h0 + VSEGH; ho += 4) {
            float4 a[4], b[4];
            #pragma unroll
            for (int i = 0; i < 4; ++i) {
                int ha = ho + i + RAD;
                a[i] = (ha < HH) ? ip[ha * STR4] : Z;
            }
            #pragma unroll
            for (int i = 0; i < 4; ++i) {
                int hb = ho + i - RAD;
                b[i] = (hb >= 0) ? ip[hb * STR4] : Z;
            }
            #pragma unroll
            for (int i = 0; i < 4; ++i) {
                S.x += a[i].x; S.y += a[i].y; S.z += a[i].z; S.w += a[i].w;
                op[(size_t)(ho + i) * STR4] = make_uint2(pk2(S.x, S.y), pk2(S.z, S.w));
                S.x -= b[i].x; S.y -= b[i].y; S.z -= b[i].z; S.w -= b[i].w;
            }
        }
    }
}

__device__ inline float wave_incl_scan(float v) {
    int lane = threadIdx.x & 63;
    #pragma unroll
    for (int d = 1; d < 64; d <<= 1) {
        float o = __shfl_up(v, d, 64);
        if (lane >= d) v += o;
    }
    return v;
}

// ---------------------------------------------------------------------------
// K2': fused middle kernel, one block per row (r8-proven, unchanged).
__global__ __launch_bounds__(256) void hmid_kernel(const unsigned* __restrict__ vsum,
                                                   const float* __restrict__ x,
                                                   unsigned* __restrict__ oh,
                                                   uint2* __restrict__ hig) {
    __shared__ float ch[2][PDW];
    __shared__ float s4[4][PDW];
    __shared__ float wtot[4];
    int t = threadIdx.x;
    size_t g = (size_t)blockIdx.x * ROWSZ;
    const uint4* vrow = (const uint4*)(vsum + (size_t)blockIdx.x * STR2);
    uint4 u = vrow[t];
    {
        float2 p0 = up2(u.x), p1 = up2(u.y), p2 = up2(u.z), p3 = up2(u.w);
        int w = 4 * t;
        ch[0][PD(w + 0)] = p0.x; ch[1][PD(w + 0)] = p0.y;
        ch[0][PD(w + 1)] = p1.x; ch[1][PD(w + 1)] = p1.y;
        ch[0][PD(w + 2)] = p2.x; ch[1][PD(w + 2)] = p2.y;
        ch[0][PD(w + 3)] = p3.x; ch[1][PD(w + 3)] = p3.y;
    }
    __syncthreads();
    {
        int c = t >> 7, j = t & 127, base = j * 8;
        float v[8]; float run = 0.f;
        #pragma unroll
        for (int i = 0; i < 8; ++i) { run += ch[c][PD(base + i)]; v[i] = run; }
        float incl = wave_incl_scan(run);
        int wid = t >> 6;
        if ((t & 63) == 63) wtot[wid] = incl;
        __syncthreads();
        float off = incl - run;
        if (wid & 1) off += wtot[wid - 1];
        #pragma unroll
        for (int i = 0; i < 8; ++i) ch[c][PD(base + i)] = off + v[i];
    }
    __syncthreads();
    const float4* xrow = (const float4*)(x + g);
    uint2* ohrow = (uint2*)(oh + (size_t)blockIdx.x * STR2);
    #pragma unroll
    for (int i = 0; i < 2; ++i) {
        int jj = t + 256 * i;
        int w0 = 2 * jj, w1 = 2 * jj + 1;
        int hi0 = w0 + RAD; if (hi0 > WW - 1) hi0 = WW - 1;
        int hi1 = w1 + RAD; if (hi1 > WW - 1) hi1 = WW - 1;
        int lo0 = w0 - RAD - 1, lo1 = w1 - RAD - 1;
        float s00 = ch[0][PD(hi0)], s10 = ch[1][PD(hi0)];
        if (lo0 >= 0) { s00 -= ch[0][PD(lo0)]; s10 -= ch[1][PD(lo0)]; }
        float s01 = ch[0][PD(hi1)], s11 = ch[1][PD(hi1)];
        if (lo1 >= 0) { s01 -= ch[0][PD(lo1)]; s11 -= ch[1][PD(lo1)]; }
        float4 xv = xrow[jj];
        float4 o;
        o.x = xv.x - SCALEV * s00; o.y = xv.y - SCALEV * s10;
        o.z = xv.z - SCALEV * s01; o.w = xv.w - SCALEV * s11;
        ohrow[jj] = make_uint2(pkh(o.x, o.y), pkh(o.z, o.w));
        s4[0][PD(w0)] = o.x;       s4[1][PD(w0)] = o.y;
        s4[0][PD(w1)] = o.z;       s4[1][PD(w1)] = o.w;
        s4[2][PD(w0)] = o.x * o.x; s4[3][PD(w0)] = o.y * o.y;
        s4[2][PD(w1)] = o.z * o.z; s4[3][PD(w1)] = o.w * o.w;
    }
    __syncthreads();
    {
        int a = t >> 6, j = t & 63, base = j * 16;
        float v[16]; float run = 0.f;
        #pragma unroll
        for (int i = 0; i < 16; ++i) { run += s4[a][PD(base + i)]; v[i] = run; }
        float incl = wave_incl_scan(run);
        float off = incl - run;
        #pragma unroll
        for (int i = 0; i < 16; ++i) s4[a][PD(base + i)] = off + v[i];
    }
    __syncthreads();
    uint4* hirow = (uint4*)(hig + (size_t)blockIdx.x * STR2);
    #pragma unroll
    for (int i = 0; i < 2; ++i) {
        int jj = t + 256 * i;
        int w0 = 2 * jj, w1 = 2 * jj + 1;
        int hi0 = w0 + RAD; if (hi0 > WW - 1) hi0 = WW - 1;
        int hi1 = w1 + RAD; if (hi1 > WW - 1) hi1 = WW - 1;
        int lo0 = w0 - RAD - 1, lo1 = w1 - RAD - 1;
        float a00 = s4[0][PD(hi0)], a10 = s4[1][PD(hi0)];
        float q00 = s4[2][PD(hi0)], q10 = s4[3][PD(hi0)];
        if (lo0 >= 0) {
            a00 -= s4[0][PD(lo0)]; a10 -= s4[1][PD(lo0)];
            q00 -= s4[2][PD(lo0)]; q10 -= s4[3][PD(lo0)];
        }
        float a01 = s4[0][PD(hi1)], a11 = s4[1][PD(hi1)];
        float q01 = s4[2][PD(hi1)], q11 = s4[3][PD(hi1)];
        if (lo1 >= 0) {
            a01 -= s4[0][PD(lo1)]; a11 -= s4[1][PD(lo1)];
            q01 -= s4[2][PD(lo1)]; q11 -= s4[3][PD(lo1)];
        }
        hirow[jj] = make_uint4(pk2(a00, a10), pk2(q00, q10),
                               pk2(a01, a11), pk2(q01, q11));
    }
}

// ---------------------------------------------------------------------------
// K3': vertical 61-box of interleaved HI (bf16) + finalize y = o/(sqrt(var)+eps).
// 16B lanes, V32 (512 blocks), fp16 numerator from OH, fp32 write-once,
// fast sqrt/rcp, double-buffered pipeline with REAL memory fences.
__global__ __launch_bounds__(256, 2) void vfinal_kernel(const uint2* __restrict__ hi,
                                                        const unsigned* __restrict__ oh,
                                                        float* __restrict__ fout) {
    int tid = blockIdx.x * 256 + threadIdx.x;
    int col = tid & (NCOL4 - 1);
    int seg = tid >> 12;
    int n = col >> 9;
    int c = col & (STR4 - 1);
    const uint4* pp = (const uint4*)(hi + (size_t)n * (size_t)HH * STR2) + c;
    const uint2* po = (const uint2*)(oh + (size_t)n * (IMGSZ / 2)) + c;
    float4* fo = (float4*)(fout + (size_t)n * IMGSZ) + c;
    int h0 = seg * VSEGH;
    float2 S1a = make_float2(0.f, 0.f), S2a = make_float2(0.f, 0.f);
    float2 S1b = make_float2(0.f, 0.f), S2b = make_float2(0.f, 0.f);
    int lo = h0 - RAD; if (lo < 0) lo = 0;
    int hiend = h0 + RAD; if (hiend > HH) hiend = HH;
    int h = lo;
    for (; h + 8 <= hiend; h += 8) {
        uint4 A[8];
        #pragma unroll
        for (int i = 0; i < 8; ++i) A[i] = pp[(h + i) * STR4];
        MEMFENCE;
        #pragma unroll
        for (int i = 0; i < 8; ++i) {
            S1a = f2add(S1a, up2(A[i].x)); S2a = f2add(S2a, up2(A[i].y));
            S1b = f2add(S1b, up2(A[i].z)); S2b = f2add(S2b, up2(A[i].w));
        }
    }
    for (; h < hiend; ++h) {
        uint4 v = pp[h * STR4];
        S1a = f2add(S1a, up2(v.x)); S2a = f2add(S2a, up2(v.y));
        S1b = f2add(S1b, up2(v.z)); S2b = f2add(S2b, up2(v.w));
    }

#define VF_ROW(Ai, Oi, Ti, ro) { \
    S1a = f2add(S1a, up2((Ai).x)); S2a = f2add(S2a, up2((Ai).y)); \
    S1b = f2add(S1b, up2((Ai).z)); S2b = f2add(S2b, up2((Ai).w)); \
    float2 oA = uph((Oi).x), oB = uph((Oi).y); \
    float4 yv; \
    yv.x = oA.x * rcp_f(sqrt_f(fmaxf(SCALEV * S2a.x - (SCALEV * S1a.x) * (SCALEV * S1a.x), 0.f)) + EPSV); \
    yv.y = oA.y * rcp_f(sqrt_f(fmaxf(SCALEV * S2a.y - (SCALEV * S1a.y) * (SCALEV * S1a.y), 0.f)) + EPSV); \
    yv.z = oB.x * rcp_f(sqrt_f(fmaxf(SCALEV * S2b.x - (SCALEV * S1b.x) * (SCALEV * S1b.x), 0.f)) + EPSV); \
    yv.w = oB.y * rcp_f(sqrt_f(fmaxf(SCALEV * S2b.y - (SCALEV * S1b.y) * (SCALEV * S1b.y), 0.f)) + EPSV); \
    oq[(ro) * STR4] = yv; \
    S1a = f2sub(S1a, up2((Ti).x)); S2a = f2sub(S2a, up2((Ti).y)); \
    S1b = f2sub(S1b, up2((Ti).z)); S2b = f2sub(S2b, up2((Ti).w)); \
}

    if (h0 >= RAD && h0 + VSEGH + RAD <= HH) {   // interior (bounds-based)
        const uint4* lp = pp + (h0 + RAD) * STR4;
        const uint4* tp = pp + (h0 - RAD) * STR4;
        const uint2* orp = po + (size_t)h0 * STR4;
        float4* oq = fo + (size_t)h0 * STR4;
        uint4 LA[8], TA[8], LB[8], TB[8];
        uint2 OA[8], OB[8];
#define VF_LOAD(Lx, Tx, Ox, r) { \
        _Pragma("unroll") for (int i = 0; i < 8; ++i) Lx[i] = lp[((r) + i) * STR4]; \
        _Pragma("unroll") for (int i = 0; i < 8; ++i) Tx[i] = tp[((r) + i) * STR4]; \
        _Pragma("unroll") for (int i = 0; i < 8; ++i) Ox[i] = orp[((r) + i) * STR4]; \
        MEMFENCE; }
#define VF_CONS(Lx, Tx, Ox, r) { \
        _Pragma("unroll") for (int i = 0; i < 8; ++i) VF_ROW(Lx[i], Ox[i], Tx[i], (r) + i) }
        VF_LOAD(LA, TA, OA, 0)
        VF_LOAD(LB, TB, OB, 8)
        VF_CONS(LA, TA, OA, 0)
        VF_LOAD(LA, TA, OA, 16)
        VF_CONS(LB, TB, OB, 8)
        VF_LOAD(LB, TB, OB, 24)
        VF_CONS(LA, TA, OA, 16)
        VF_CONS(LB, TB, OB, 24)
#undef VF_LOAD
#undef VF_CONS
    } else {
        const uint4 Z4 = make_uint4(0u, 0u, 0u, 0u);
        float4* oq = fo;   // absolute row index used below
        for (int ho = h0; ho < h0 + VSEGH; ho += 4) {
            uint4 a[4], b[4];
            uint2 O[4];
            #pragma unroll
            for (int i = 0; i < 4; ++i) {
                int ha = ho + i + RAD;
                a[i] = (ha < HH) ? pp[ha * STR4] : Z4;
            }
            #pragma unroll
            for (int i = 0; i < 4; ++i) {
                int hb = ho + i - RAD;
                b[i] = (hb >= 0) ? pp[hb * STR4] : Z4;
            }
            #pragma unroll
            for (int i = 0; i < 4; ++i) O[i] = po[(size_t)(ho + i) * STR4];
            #pragma unroll
            for (int i = 0; i < 4; ++i) {
                VF_ROW(a[i], O[i], b[i], (size_t)(ho + i))
            }
        }
        (void)oq;
    }
#undef VF_ROW
}

extern "C" void kernel_launch(void* const* d_in, const int* in_sizes, int n_in,
                              void* d_out, int out_size, void* d_ws, size_t ws_size,
                              hipStream_t stream) {
    const float* x = (const float*)d_in[0];
    float* out = (float*)d_out;
    unsigned* V1 = (unsigned*)d_ws;                       // 32 MB bf16 vbox(x); later ALIASED as fp16 OH
    unsigned* OH = V1;                                    // fp16 numerator plane (same rows, same size)
    uint2* HI = (uint2*)(V1 + (size_t)NB * IMGSZ / 2);    // 64 MB interleaved Hbox(out), Hbox(out^2)

    int vgrid = (NCOL4 * VNSEG) / 256;                    // 512 blocks
    vbox_kernel<<<vgrid, 256, 0, stream>>>(x, V1);
    hmid_kernel<<<NB * HH, 256, 0, stream>>>(V1, x, OH, HI);
    vfinal_kernel<<<vgrid, 256, 0, stream>>>(HI, OH, out);
}